// Round 14
// baseline (354.687 us; speedup 1.0000x reference)
//
#include <hip/hip_runtime.h>
#include <math.h>

#define DIM 128
#define NRES 262144

typedef __attribute__((ext_vector_type(8))) short short8;
typedef __attribute__((ext_vector_type(4))) float f32x4;

__device__ __forceinline__ float sigmoidf_(float x) {
    return 1.0f / (1.0f + __expf(-x));
}
__device__ __forceinline__ float tanhf_(float x) {
    return 1.0f - 2.0f / (__expf(2.0f * x) + 1.0f);
}
__device__ __forceinline__ unsigned short f2bf(float f) {
    unsigned int u = __float_as_uint(f);
    unsigned int r = u + 0x7FFFu + ((u >> 16) & 1u);
    return (unsigned short)(r >> 16);
}

// W f32 [640][256] -> FRAGMENT-ORDERED bf16 Wb.
// short8 element i = (w,g,kc,lane): i = ((w*5+g)*8+kc)*64 + lane,
// lane = kg*16+col; source = W[g*128+w*16+col][kc*32+kg*8 .. +8].
// => a wave's B-fragment load for (g,kc) is 64 lanes x 16B CONTIGUOUS (1KB).
__global__ void convert_w_kernel(const float* __restrict__ W, unsigned short* __restrict__ Wb) {
    int i = blockIdx.x * 256 + threadIdx.x;   // 0..20479
    int l = i & 63;
    int kc = (i >> 6) & 7;
    int gw = i >> 9;            // w*5+g, 0..39
    int g = gw % 5;
    int w = gw / 5;
    int col = l & 15, kg = l >> 4;
    const float* s = W + (size_t)(g * 128 + w * 16 + col) * 256 + kc * 32 + kg * 8;
    float4 u0 = *(const float4*)s;
    float4 u1 = *(const float4*)(s + 4);
    unsigned short o[8] = {f2bf(u0.x), f2bf(u0.y), f2bf(u0.z), f2bf(u0.w),
                           f2bf(u1.x), f2bf(u1.y), f2bf(u1.z), f2bf(u1.w)};
    *(short8*)(Wb + (size_t)i * 8) = *(short8*)o;
}

// ---- 4-level fused tree-LSTM pass ----
// Round-13 structure with ONE change: level-0 c-output moves from 16 VGPRs
// (cst0) to LDS C0f (f32, stride 128). Unified regs ~80+40acc=120 <= 128 ->
// 4 waves/SIMD; LDS 32+16+32 = 80KB -> exactly 2 blocks/CU on both budgets
// (round 13: 136 regs -> 12 waves -> 1 block/CU, occupancy 23%).
// B streams from fragment-ordered Wb (contiguous 1KB wave-loads, L2-hot).
// c levels 1-3 stay in registers, moved parent->child via __shfl.
// LEAF pass fuses the coalesced leaves-output write-through.
template<int AR, bool LEAF, bool LASTPASS>
__global__ __launch_bounds__(512)
void fused4_kernel(const void* __restrict__ x_in,
                   const float* __restrict__ c_in,
                   const unsigned short* __restrict__ Wb,
                   const float* __restrict__ bvec,
                   unsigned short* __restrict__ h_out,
                   float* __restrict__ c_out,
                   float* __restrict__ out) {
    __shared__ __align__(16) unsigned short HA[AR * 256];
    __shared__ __align__(16) unsigned short HB[(AR / 2) * 256];
    __shared__ float C0f[AR * 128];   // level-0 c-out, f32
    __shared__ float ROOTS[512];      // only instantiated when LASTPASS

    const int t = threadIdx.x;
    const int lane = t & 63;
    const int wid = t >> 6;
    const int col = lane & 15;
    const int kg = lane >> 4;
    const int d = wid * 16 + col;

    float bias[5];
    #pragma unroll
    for (int g = 0; g < 5; ++g) bias[g] = bvec[g * 128 + d];

    // ---- stage AR A-rows into HA
    if (LEAF) {
        const float* xf = (const float*)x_in + (size_t)blockIdx.x * (AR * 256);
        float* outw = out + 256 + (size_t)blockIdx.x * (AR * 512);
        #pragma unroll
        for (int i = 0; i < AR / 16; ++i) {
            int j = i * 512 + t;       // 16B-chunk id
            int r = j >> 5, c = j & 31;
            const float* s = xf + r * 256 + c * 8;
            float4 u0 = *(const float4*)s;
            float4 u1 = *(const float4*)(s + 4);
            unsigned short o[8] = {f2bf(u0.x), f2bf(u0.y), f2bf(u0.z), f2bf(u0.w),
                                   f2bf(u1.x), f2bf(u1.y), f2bf(u1.z), f2bf(u1.w)};
            *(short8*)&HA[r * 256 + ((c ^ (r & 7)) * 8)] = *(short8*)o;
            // fused leaves write-through
            int l = 2 * r + (c >> 4);
            float* wdst = outw + (size_t)l * 256 + (c & 15) * 8;
            float4 z4 = make_float4(0.f, 0.f, 0.f, 0.f);
            *(float4*)wdst = u0;
            *(float4*)(wdst + 4) = u1;
            *(float4*)(wdst + 128) = z4;
            *(float4*)(wdst + 132) = z4;
        }
    } else {
        const unsigned short* xb = (const unsigned short*)x_in + (size_t)blockIdx.x * (AR * 256);
        #pragma unroll
        for (int i = 0; i < AR / 16; ++i) {
            int j0 = i * 512 + wid * 64;
            int j = j0 + lane;
            int r = j >> 5, c = j & 31;
            __builtin_amdgcn_global_load_lds(
                (const __attribute__((address_space(1))) unsigned int*)(xb + (size_t)r * 256 + ((c ^ (r & 7)) * 8)),
                (__attribute__((address_space(3))) unsigned int*)&HA[j0 * 8],
                16, 0, 0);
        }
    }
    __syncthreads();

    // c-state registers for levels 1-3 (level 0 uses LDS C0f)
    float cst1[2][4] = {};
    float cst2[1][4] = {};

// B from fragment-ordered Wb: per (g,kc) one coalesced 1KB wave-load from L2
#define CHUNK(HS, AROW0, MF, ACC) do {                                                   \
    _Pragma("unroll")                                                                    \
    for (int kc = 0; kc < 8; ++kc) {                                                     \
        short8 bfr[5];                                                                   \
        _Pragma("unroll")                                                                \
        for (int g = 0; g < 5; ++g)                                                      \
            bfr[g] = *(const short8*)(Wb + ((size_t)((wid * 5 + g) * 8 + kc) * 64 + lane) * 8); \
        _Pragma("unroll")                                                                \
        for (int mf = 0; mf < (MF); ++mf) {                                              \
            int ar = (AROW0) + mf * 16 + col;                                            \
            int q = (kc * 4 + kg) ^ (ar & 7);                                            \
            short8 a = *(const short8*)&(HS)[ar * 256 + q * 8];                          \
            _Pragma("unroll")                                                            \
            for (int g = 0; g < 5; ++g)                                                  \
                (ACC)[mf][g] = __builtin_amdgcn_mfma_f32_16x16x32_bf16(a, bfr[g], (ACC)[mf][g], 0, 0, 0); \
        }                                                                                \
    }                                                                                    \
} while (0)

// CMODE: 0 zero-c | 1 global c_in | 2 shuffle regs CSTC | 3 LDS C0f
// CSINK: 0 LDS C0f | 1 reg array CSTN
// SINKMODE: 0 lds HDP + c-sink | 1 global h_out/c_out | 2 ROOTS
#define EPIX(MF, PL, CHBASE, CMODE, CSTC, CSINK, CSTN, SINKMODE, HDP, ACC) do {          \
    _Pragma("unroll")                                                                    \
    for (int mf = 0; mf < (MF); ++mf) {                                                  \
        _Pragma("unroll")                                                                \
        for (int r4 = 0; r4 < 4; ++r4) {                                                 \
            const int P = (CHBASE) + mf * 16 + kg * 4 + r4;                              \
            float cl = 0.f, cr = 0.f;                                                    \
            if ((CMODE) == 1) {                                                          \
                size_t cb = ((size_t)blockIdx.x * (2 * AR) + 2 * (size_t)P) * 128 + d;   \
                cl = c_in[cb]; cr = c_in[cb + 128];                                      \
            } else if ((CMODE) == 2) {                                                   \
                const int mfa = (CHBASE) / 16 + mf;                                      \
                const int lo = 2 * mfa;                                                  \
                const int hi = 2 * mfa + 1;                                              \
                {   const int e = (2 * r4) >> 2, rq = (2 * r4) & 3;                      \
                    int srcl = (((2 * kg + e) & 3) << 4) + col;                          \
                    float va = __shfl((CSTC)[lo][rq], srcl);                             \
                    float vb = __shfl((CSTC)[hi][rq], srcl);                             \
                    cl = (kg < 2) ? va : vb; }                                           \
                {   const int e = (2 * r4 + 1) >> 2, rq = (2 * r4 + 1) & 3;              \
                    int srcl = (((2 * kg + e) & 3) << 4) + col;                          \
                    float va = __shfl((CSTC)[lo][rq], srcl);                             \
                    float vb = __shfl((CSTC)[hi][rq], srcl);                             \
                    cr = (kg < 2) ? va : vb; }                                           \
            } else if ((CMODE) == 3) {                                                   \
                cl = C0f[(2 * P) * 128 + d];                                             \
                cr = C0f[(2 * P + 1) * 128 + d];                                         \
            }                                                                            \
            float iv = sigmoidf_((ACC)[mf][0][r4] + bias[0]);                            \
            float fl = sigmoidf_((ACC)[mf][1][r4] + bias[1]);                            \
            float fr = sigmoidf_((ACC)[mf][2][r4] + bias[2]);                            \
            float ov = sigmoidf_((ACC)[mf][3][r4] + bias[3]);                            \
            float gv = tanhf_((ACC)[mf][4][r4] + bias[4]);                               \
            float cn = fl * cl + fr * cr + iv * gv;                                      \
            float hn = ov * tanhf_(cn);                                                  \
            if (P < (PL)) {                                                              \
                if ((SINKMODE) == 0) {                                                   \
                    if ((CSINK) == 0) C0f[P * 128 + d] = cn;                             \
                    else (CSTN)[((CHBASE) / 16 + mf) & 1][r4] = cn;                      \
                    int rw = P >> 1;                                                     \
                    int cc = (((P & 1) * 16) + (d >> 3)) ^ (rw & 7);                     \
                    (HDP)[rw * 256 + cc * 8 + (d & 7)] = f2bf(hn);                       \
                } else if ((SINKMODE) == 1) {                                            \
                    size_t oo = ((size_t)blockIdx.x * (AR / 8) + P) * 128 + d;           \
                    h_out[oo] = f2bf(hn); c_out[oo] = cn;                                \
                } else {                                                                 \
                    ROOTS[P * 128 + d] = hn;                                             \
                }                                                                        \
            }                                                                            \
        }                                                                                \
    }                                                                                    \
} while (0)

    // ---------------- Level 0: parents = AR -> c to LDS C0f ----------------
    {
        f32x4 acc[2][5] = {};
        CHUNK(HA, 0, 2, acc);
        EPIX(2, AR, 0, (LEAF ? 0 : 1), cst1, 0, cst1, 0, HB, acc);
        if constexpr (AR == 64) {
            f32x4 acc2[2][5] = {};
            CHUNK(HA, 32, 2, acc2);
            EPIX(2, AR, 32, (LEAF ? 0 : 1), cst1, 0, cst1, 0, HB, acc2);
        }
    }
    __syncthreads();

    // ---------------- Level 1: parents = AR/2, c from LDS C0f ----------------
    {
        f32x4 acc[2][5] = {};
        if constexpr (AR == 64) {
            CHUNK(HB, 0, 2, acc);
            EPIX(2, 32, 0, 3, cst1, 1, cst1, 0, HA, acc);
        } else {
            CHUNK(HB, 0, 1, acc);
            EPIX(1, 16, 0, 3, cst1, 1, cst1, 0, HA, acc);
        }
    }
    __syncthreads();

    // ---------------- Level 2: parents = AR/4, c from cst1 shuffles ----------------
    {
        f32x4 acc[2][5] = {};
        CHUNK(HA, 0, 1, acc);
        EPIX(1, AR / 4, 0, 2, cst1, 1, cst2, 0, HB, acc);
    }
    __syncthreads();

    // ---------------- Level 3: parents = AR/8 -> out, c from cst2 ----------------
    {
        f32x4 acc[2][5] = {};
        CHUNK(HB, 0, 1, acc);
        if constexpr (LASTPASS) {
            EPIX(1, AR / 8, 0, 2, cst2, 1, cst2, 2, HA, acc);
        } else {
            EPIX(1, AR / 8, 0, 2, cst2, 1, cst2, 1, HA, acc);
        }
    }

    if constexpr (LASTPASS) {
        __syncthreads();
        if (t < 128) {
            out[t] = 0.25f * (ROOTS[t] + ROOTS[128 + t] + ROOTS[256 + t] + ROOTS[384 + t]);
        } else if (t < 256) {
            out[t] = 0.0f;
        }
    }
#undef CHUNK
#undef EPIX
}

extern "C" void kernel_launch(void* const* d_in, const int* in_sizes, int n_in,
                              void* d_out, int out_size, void* d_ws, size_t ws_size,
                              hipStream_t stream) {
    const float* leaf = (const float*)d_in[0];
    const float* W_up = (const float*)d_in[1];
    const float* b_up = (const float*)d_in[2];
    float* out = (float*)d_out;
    char* ws = (char*)d_ws;

    unsigned short* Wb = (unsigned short*)ws;                  // 320 KB (fragment-ordered)
    unsigned short* h1 = (unsigned short*)(ws + 0x100000);     // 16384x128 bf16 = 4 MB
    float* c1 = (float*)(ws + 0x500000);                       // 16384x128 f32 = 8 MB
    unsigned short* h2 = (unsigned short*)(ws + 0xD00000);     // 1024x128 bf16
    float* c2 = (float*)(ws + 0xD40000);                       // 512 KB
    unsigned short* h3 = (unsigned short*)(ws + 0xDC0000);     // 64x128 bf16
    float* c3 = (float*)(ws + 0xDC8000);                       // 32 KB

    convert_w_kernel<<<80, 256, 0, stream>>>(W_up, Wb);

    // P1: 262144 leaves -> 16384 rows (levels 1-4) + leaves write-through
    fused4_kernel<64, true, false><<<2048, 512, 0, stream>>>(leaf, nullptr, Wb, b_up, h1, c1, out);
    // P2: 16384 -> 1024 (levels 5-8)
    fused4_kernel<64, false, false><<<128, 512, 0, stream>>>(h1, c1, Wb, b_up, h2, c2, nullptr);
    // P3: 1024 -> 64 (levels 9-12)
    fused4_kernel<64, false, false><<<8, 512, 0, stream>>>(h2, c2, Wb, b_up, h3, c3, nullptr);
    // P4: 64 -> 4 roots (levels 13-16) + mean + out[128:256]=0
    fused4_kernel<32, false, true><<<1, 512, 0, stream>>>(h3, c3, Wb, b_up, nullptr, nullptr, out);
}

// Round 15
// 351.750 us; speedup vs baseline: 1.0084x; 1.0084x over previous
//
#include <hip/hip_runtime.h>
#include <math.h>

#define DIM 128
#define NRES 262144

typedef __attribute__((ext_vector_type(8))) short short8;
typedef __attribute__((ext_vector_type(4))) float f32x4;

__device__ __forceinline__ float sigmoidf_(float x) {
    return 1.0f / (1.0f + __expf(-x));
}
__device__ __forceinline__ float tanhf_(float x) {
    return 1.0f - 2.0f / (__expf(2.0f * x) + 1.0f);
}
__device__ __forceinline__ unsigned short f2bf(float f) {
    unsigned int u = __float_as_uint(f);
    unsigned int r = u + 0x7FFFu + ((u >> 16) & 1u);
    return (unsigned short)(r >> 16);
}

// W f32 [640][256] -> FRAGMENT-ORDERED bf16 Wb (validated round 13):
// short8 i = ((w*5+g)*8+kc)*64 + lane; lane=kg*16+col;
// src = W[g*128+w*16+col][kc*32+kg*8 ..+8]. Wave B-load = contiguous 1KB.
__global__ void convert_w_kernel(const float* __restrict__ W, unsigned short* __restrict__ Wb) {
    int i = blockIdx.x * 256 + threadIdx.x;   // 0..20479
    int l = i & 63;
    int kc = (i >> 6) & 7;
    int gw = i >> 9;
    int g = gw % 5;
    int w = gw / 5;
    int col = l & 15, kg = l >> 4;
    const float* s = W + (size_t)(g * 128 + w * 16 + col) * 256 + kc * 32 + kg * 8;
    float4 u0 = *(const float4*)s;
    float4 u1 = *(const float4*)(s + 4);
    unsigned short o[8] = {f2bf(u0.x), f2bf(u0.y), f2bf(u0.z), f2bf(u0.w),
                           f2bf(u1.x), f2bf(u1.y), f2bf(u1.z), f2bf(u1.w)};
    *(short8*)(Wb + (size_t)i * 8) = *(short8*)o;
}

// ---- 4-level fused tree-LSTM pass, all-LDS c with region aliasing ----
// LDS = HA 2*AR*... (AR*512B) + HB (AR/2*512B) + C0a 16KB = 64KB @ AR=64 ->
// comfortably 2 blocks/CU (prev rounds: 80KB/128regs = exact boundary = 1 blk).
// c-arena aliases (phase-safe; c-addresses are column-private per wave):
//   c0 rows 0-31 -> C0a; c0 rows 32-63 -> (float*)HA [0,16K)   [after mid-L0 bar]
//   c1 (32 rows) -> (float*)HA + 4096  [16K,32K)               [HA dead]
//   h1 -> HB[0,8K)                                              [L1 CHUNK/EPI bar]
//   c2 (16 rows) -> C0a[0,8K); h2 -> HA[0,4K)                   [all dead]
//   ROOTS -> C0a + 2048 ([8K,10K))                               [LASTPASS]
// B streams from fragment-ordered Wb (contiguous 1KB wave-loads, L2-hot).
template<int AR, bool LEAF, bool LASTPASS>
__global__ __launch_bounds__(512)
void fused4_kernel(const void* __restrict__ x_in,
                   const float* __restrict__ c_in,
                   const unsigned short* __restrict__ Wb,
                   const float* __restrict__ bvec,
                   unsigned short* __restrict__ h_out,
                   float* __restrict__ c_out,
                   float* __restrict__ out) {
    __shared__ __align__(16) unsigned short HA[AR * 256];
    __shared__ __align__(16) unsigned short HB[(AR / 2) * 256];
    __shared__ __align__(16) float C0a[32 * 128];   // 16 KB

    float* const C0b = (float*)HA;                          // c0 rows 32-63 (AR=64)
    float* const C1 = (float*)HA + (AR == 64 ? 4096 : 2048);
    float* const C2 = C0a;
    float* const ROOTSp = C0a + (AR == 64 ? 2048 : 1024);

    const int t = threadIdx.x;
    const int lane = t & 63;
    const int wid = t >> 6;
    const int col = lane & 15;
    const int kg = lane >> 4;
    const int d = wid * 16 + col;

    float bias[5];
    #pragma unroll
    for (int g = 0; g < 5; ++g) bias[g] = bvec[g * 128 + d];

    // ---- stage AR A-rows into HA (row-major, chunk-XOR swizzle)
    if (LEAF) {
        const float* xf = (const float*)x_in + (size_t)blockIdx.x * (AR * 256);
        float* outw = out + 256 + (size_t)blockIdx.x * (AR * 512);
        #pragma unroll
        for (int i = 0; i < AR / 16; ++i) {
            int j = i * 512 + t;
            int r = j >> 5, c = j & 31;
            const float* s = xf + r * 256 + c * 8;
            float4 u0 = *(const float4*)s;
            float4 u1 = *(const float4*)(s + 4);
            unsigned short o[8] = {f2bf(u0.x), f2bf(u0.y), f2bf(u0.z), f2bf(u0.w),
                                   f2bf(u1.x), f2bf(u1.y), f2bf(u1.z), f2bf(u1.w)};
            *(short8*)&HA[r * 256 + ((c ^ (r & 7)) * 8)] = *(short8*)o;
            // fused leaves write-through (coalesced)
            int l = 2 * r + (c >> 4);
            float* wdst = outw + (size_t)l * 256 + (c & 15) * 8;
            float4 z4 = make_float4(0.f, 0.f, 0.f, 0.f);
            *(float4*)wdst = u0;
            *(float4*)(wdst + 4) = u1;
            *(float4*)(wdst + 128) = z4;
            *(float4*)(wdst + 132) = z4;
        }
    } else {
        const unsigned short* xb = (const unsigned short*)x_in + (size_t)blockIdx.x * (AR * 256);
        #pragma unroll
        for (int i = 0; i < AR / 16; ++i) {
            int j0 = i * 512 + wid * 64;
            int j = j0 + lane;
            int r = j >> 5, c = j & 31;
            __builtin_amdgcn_global_load_lds(
                (const __attribute__((address_space(1))) unsigned int*)(xb + (size_t)r * 256 + ((c ^ (r & 7)) * 8)),
                (__attribute__((address_space(3))) unsigned int*)&HA[j0 * 8],
                16, 0, 0);
        }
    }
    __syncthreads();

#define CHUNK(HS, AROW0, MF, ACC) do {                                                   \
    _Pragma("unroll")                                                                    \
    for (int kc = 0; kc < 8; ++kc) {                                                     \
        short8 bfr[5];                                                                   \
        _Pragma("unroll")                                                                \
        for (int g = 0; g < 5; ++g)                                                      \
            bfr[g] = *(const short8*)(Wb + ((size_t)((wid * 5 + g) * 8 + kc) * 64 + lane) * 8); \
        _Pragma("unroll")                                                                \
        for (int mf = 0; mf < (MF); ++mf) {                                              \
            int ar = (AROW0) + mf * 16 + col;                                            \
            int q = (kc * 4 + kg) ^ (ar & 7);                                            \
            short8 a = *(const short8*)&(HS)[ar * 256 + q * 8];                          \
            _Pragma("unroll")                                                            \
            for (int g = 0; g < 5; ++g)                                                  \
                (ACC)[mf][g] = __builtin_amdgcn_mfma_f32_16x16x32_bf16(a, bfr[g], (ACC)[mf][g], 0, 0, 0); \
        }                                                                                \
    }                                                                                    \
} while (0)

// CMODE: 0 zero-c | 1 global c_in | 2 LDS (CLO rows<SPLIT, CHI rows>=SPLIT)
// SINK:  0 LDS (h->HDP, c->CSNK+(P-CB)*128) | 1 global h_out/c_out | 2 ROOTSp
#define EPI(MF, PL, CHBASE, CMODE, CLO, CHI, SPLIT, SINK, HDP, CSNK, CB, ACC) do {       \
    _Pragma("unroll")                                                                    \
    for (int mf = 0; mf < (MF); ++mf) {                                                  \
        _Pragma("unroll")                                                                \
        for (int r4 = 0; r4 < 4; ++r4) {                                                 \
            const int P = (CHBASE) + mf * 16 + kg * 4 + r4;                              \
            if (P < (PL)) {                                                              \
                float cl = 0.f, cr = 0.f;                                                \
                if ((CMODE) == 1) {                                                      \
                    size_t cb = ((size_t)blockIdx.x * (2 * AR) + 2 * (size_t)P) * 128 + d; \
                    cl = c_in[cb]; cr = c_in[cb + 128];                                  \
                } else if ((CMODE) == 2) {                                               \
                    int r0 = 2 * P, r1 = 2 * P + 1;                                      \
                    const float* p0 = (r0 < (SPLIT)) ? (CLO) + r0 * 128 : (CHI) + (r0 - (SPLIT)) * 128; \
                    const float* p1 = (r1 < (SPLIT)) ? (CLO) + r1 * 128 : (CHI) + (r1 - (SPLIT)) * 128; \
                    cl = p0[d]; cr = p1[d];                                              \
                }                                                                        \
                float iv = sigmoidf_((ACC)[mf][0][r4] + bias[0]);                        \
                float fl = sigmoidf_((ACC)[mf][1][r4] + bias[1]);                        \
                float fr = sigmoidf_((ACC)[mf][2][r4] + bias[2]);                        \
                float ov = sigmoidf_((ACC)[mf][3][r4] + bias[3]);                        \
                float gv = tanhf_((ACC)[mf][4][r4] + bias[4]);                           \
                float cn = fl * cl + fr * cr + iv * gv;                                  \
                float hn = ov * tanhf_(cn);                                              \
                if ((SINK) == 0) {                                                       \
                    (CSNK)[(P - (CB)) * 128 + d] = cn;                                   \
                    int rw = P >> 1;                                                     \
                    int cc = (((P & 1) * 16) + (d >> 3)) ^ (rw & 7);                     \
                    (HDP)[rw * 256 + cc * 8 + (d & 7)] = f2bf(hn);                       \
                } else if ((SINK) == 1) {                                                \
                    size_t oo = ((size_t)blockIdx.x * (AR / 8) + P) * 128 + d;           \
                    h_out[oo] = f2bf(hn); c_out[oo] = cn;                                \
                } else {                                                                 \
                    ROOTSp[P * 128 + d] = hn;                                            \
                }                                                                        \
            }                                                                            \
        }                                                                                \
    }                                                                                    \
} while (0)

    // ---- Level 0, half A: parents 0..31 (c -> C0a, h -> HB)
    {
        f32x4 acc[2][5] = {};
        CHUNK(HA, 0, 2, acc);
        EPI(2, AR, 0, (LEAF ? 0 : 1), C0a, C0a, 64, 0, HB, C0a, 0, acc);
    }
    if constexpr (AR == 64) {
        // mid-L0 barrier: all HA[0,16K) reads done -> C0b may alias it
        __syncthreads();
        f32x4 acc[2][5] = {};
        CHUNK(HA, 32, 2, acc);
        EPI(2, AR, 32, (LEAF ? 0 : 1), C0a, C0a, 64, 0, HB, C0b, 32, acc);
    }
    __syncthreads();

    // ---- Level 1: parents AR/2 (c-src C0a/C0b; h -> HB/HA; c1 -> C1)
    {
        f32x4 acc[2][5] = {};
        if constexpr (AR == 64) {
            CHUNK(HB, 0, 2, acc);
            __syncthreads();   // HB reads done -> h1 may overwrite HB[0,8K)
            EPI(2, 32, 0, 2, C0a, C0b, 32, 0, HB, C1, 0, acc);
        } else {
            CHUNK(HB, 0, 1, acc);
            EPI(1, 16, 0, 2, C0a, C0a, 64, 0, HA, C1, 0, acc);
        }
    }
    __syncthreads();

    // ---- Level 2: parents AR/4 (c-src C1; h -> HA/HB; c2 -> C2=C0a)
    {
        f32x4 acc[1][5] = {};
        if constexpr (AR == 64) {
            CHUNK(HB, 0, 1, acc);
            EPI(1, 16, 0, 2, C1, C1, 64, 0, HA, C2, 0, acc);
        } else {
            CHUNK(HA, 0, 1, acc);
            EPI(1, 8, 0, 2, C1, C1, 64, 0, HB, C2, 0, acc);
        }
    }
    __syncthreads();

    // ---- Level 3: parents AR/8 -> global or ROOTS (c-src C2)
    {
        f32x4 acc[1][5] = {};
        if constexpr (AR == 64) {
            CHUNK(HA, 0, 1, acc);
        } else {
            CHUNK(HB, 0, 1, acc);
        }
        if constexpr (LASTPASS) {
            EPI(1, AR / 8, 0, 2, C2, C2, 64, 2, HA, C2, 0, acc);
        } else {
            EPI(1, AR / 8, 0, 2, C2, C2, 64, 1, HA, C2, 0, acc);
        }
    }

    if constexpr (LASTPASS) {
        __syncthreads();
        if (t < 128) {
            out[t] = 0.25f * (ROOTSp[t] + ROOTSp[128 + t] + ROOTSp[256 + t] + ROOTSp[384 + t]);
        } else if (t < 256) {
            out[t] = 0.0f;
        }
    }
#undef CHUNK
#undef EPI
}

extern "C" void kernel_launch(void* const* d_in, const int* in_sizes, int n_in,
                              void* d_out, int out_size, void* d_ws, size_t ws_size,
                              hipStream_t stream) {
    const float* leaf = (const float*)d_in[0];
    const float* W_up = (const float*)d_in[1];
    const float* b_up = (const float*)d_in[2];
    float* out = (float*)d_out;
    char* ws = (char*)d_ws;

    unsigned short* Wb = (unsigned short*)ws;                  // 320 KB (fragment-ordered)
    unsigned short* h1 = (unsigned short*)(ws + 0x100000);     // 16384x128 bf16 = 4 MB
    float* c1 = (float*)(ws + 0x500000);                       // 16384x128 f32 = 8 MB
    unsigned short* h2 = (unsigned short*)(ws + 0xD00000);     // 1024x128 bf16
    float* c2 = (float*)(ws + 0xD40000);                       // 512 KB
    unsigned short* h3 = (unsigned short*)(ws + 0xDC0000);     // 64x128 bf16
    float* c3 = (float*)(ws + 0xDC8000);                       // 32 KB

    convert_w_kernel<<<80, 256, 0, stream>>>(W_up, Wb);

    // P1: 262144 leaves -> 16384 rows (levels 1-4) + leaves write-through
    fused4_kernel<64, true, false><<<2048, 512, 0, stream>>>(leaf, nullptr, Wb, b_up, h1, c1, out);
    // P2: 16384 -> 1024 (levels 5-8)
    fused4_kernel<64, false, false><<<128, 512, 0, stream>>>(h1, c1, Wb, b_up, h2, c2, nullptr);
    // P3: 1024 -> 64 (levels 9-12)
    fused4_kernel<64, false, false><<<8, 512, 0, stream>>>(h2, c2, Wb, b_up, h3, c3, nullptr);
    // P4: 64 -> 4 roots (levels 13-16) + mean + out[128:256]=0
    fused4_kernel<32, false, true><<<1, 512, 0, stream>>>(h3, c3, Wb, b_up, nullptr, nullptr, out);
}